// Round 5
// baseline (76.771 us; speedup 1.0000x reference)
//
#include <hip/hip_runtime.h>

#define VOCAB 4000
#define UNIQ 30000
#define MIDN 12
#define HID 256
#define OUT 768
#define BATCH 16
#define SEQ 2048

#define NSLICE 8
#define SCOLS 96            // OUT / NSLICE
#define TOKS_PER_BLK 128
#define PASSES 8            // 16 tokens per pass * 8 = 128

typedef __attribute__((ext_vector_type(8))) short short8;   // 8 bf16 = 16B
typedef __attribute__((ext_vector_type(4))) float f32x4;
typedef __attribute__((ext_vector_type(4))) unsigned int u32x4;

__device__ __forceinline__ float bitsf(unsigned int x) {
    float f; __builtin_memcpy(&f, &x, 4); return f;
}
__device__ __forceinline__ unsigned short f2bf(float f) {
    unsigned int x;
    __builtin_memcpy(&x, &f, 4);
    x += 0x7fff + ((x >> 16) & 1);   // round-to-nearest-even
    return (unsigned short)(x >> 16);
}

// ---------------------------------------------------------------------------
// build_ids: idsU[u][16] int16 = [first[u], mid[u,:]+4000, last[u]+8000, 0, 0]
// ---------------------------------------------------------------------------
__global__ __launch_bounds__(256) void build_ids(
    const int* __restrict__ first, const int* __restrict__ mid,
    const int* __restrict__ last, short* __restrict__ idsU)
{
    int u = blockIdx.x * 256 + threadIdx.x;
    if (u >= UNIQ) return;
    short ids[16];
    ids[0] = (short)first[u];
    #pragma unroll
    for (int m = 0; m < MIDN; ++m)
        ids[1 + m] = (short)(mid[u * MIDN + m] + VOCAB);
    ids[13] = (short)(last[u] + 2 * VOCAB);
    ids[14] = 0; ids[15] = 0;
    *reinterpret_cast<short8*>(&idsU[(size_t)u * 16])     = *reinterpret_cast<short8*>(&ids[0]);
    *reinterpret_cast<short8*>(&idsU[(size_t)u * 16 + 8]) = *reinterpret_cast<short8*>(&ids[8]);
}

// ---------------------------------------------------------------------------
// conv_w: W (768x768 fp32) -> Wt bf16 [3][768][256] via LDS transpose tiles.
// ---------------------------------------------------------------------------
__global__ __launch_bounds__(256) void conv_w(
    const float* __restrict__ W, unsigned short* __restrict__ Wt)
{
    __shared__ float T[32][33];
    const int s  = blockIdx.z;
    const int n0 = blockIdx.x * 32;
    const int h0 = blockIdx.y * 32;
    const int tx = threadIdx.x & 31;
    const int ty = threadIdx.x >> 5;

    #pragma unroll
    for (int k = 0; k < 4; ++k) {
        int h = ty + 8 * k;
        T[h][tx] = W[(size_t)(s * HID + h0 + h) * OUT + n0 + tx];
    }
    __syncthreads();
    #pragma unroll
    for (int k = 0; k < 4; ++k) {
        int n = ty + 8 * k;
        Wt[(size_t)(s * OUT + n0 + n) * HID + h0 + tx] = f2bf(T[tx][n]);
    }
}

// ---------------------------------------------------------------------------
// proj_mfma: P_sliced[sl][s][v][c] = sum_h E[v][h] * W[s*256+h][sl*96+c]
// 128x128 tile, 4 waves, BK=32, mfma_f32_16x16x32_bf16.
// ---------------------------------------------------------------------------
__global__ __launch_bounds__(256) void proj_mfma(
    const float* __restrict__ E,
    const unsigned short* __restrict__ Wt,
    unsigned short* __restrict__ P)
{
    const int s  = blockIdx.z;
    const int n0 = blockIdx.x * 128;
    const int m0 = blockIdx.y * 128;
    const unsigned short* Wts = Wt + (size_t)s * OUT * HID;

    __shared__ short As[128][40];   // 80B pitch
    __shared__ short Bs[128][40];

    const int tid  = threadIdx.x;
    const int lane = tid & 63;
    const int w    = tid >> 6;
    const int wm   = w >> 1;
    const int wn   = w & 1;
    const int lo   = lane & 15;
    const int hi   = lane >> 4;

    f32x4 acc[4][4] = {};

    for (int kt = 0; kt < HID; kt += 32) {
        #pragma unroll
        for (int p = 0; p < 2; ++p) {
            int idx = p * 256 + tid;
            int row = idx >> 2;
            int ko  = (idx & 3) * 8;
            int gm  = m0 + row;
            f32x4 e0 = {}, e1 = {};
            if (gm < VOCAB) {
                e0 = *reinterpret_cast<const f32x4*>(&E[(size_t)gm * HID + kt + ko]);
                e1 = *reinterpret_cast<const f32x4*>(&E[(size_t)gm * HID + kt + ko + 4]);
            }
            short8 v;
            v[0] = (short)f2bf(e0.x); v[1] = (short)f2bf(e0.y);
            v[2] = (short)f2bf(e0.z); v[3] = (short)f2bf(e0.w);
            v[4] = (short)f2bf(e1.x); v[5] = (short)f2bf(e1.y);
            v[6] = (short)f2bf(e1.z); v[7] = (short)f2bf(e1.w);
            *reinterpret_cast<short8*>(&As[row][ko]) = v;
        }
        #pragma unroll
        for (int p = 0; p < 2; ++p) {
            int idx = p * 256 + tid;
            int col = idx >> 2;
            int ko  = (idx & 3) * 8;
            short8 v = *reinterpret_cast<const short8*>(
                &Wts[(size_t)(n0 + col) * HID + kt + ko]);
            *reinterpret_cast<short8*>(&Bs[col][ko]) = v;
        }
        __syncthreads();

        short8 a[4], b[4];
        #pragma unroll
        for (int f = 0; f < 4; ++f)
            a[f] = *reinterpret_cast<short8*>(&As[wm * 64 + f * 16 + lo][hi * 8]);
        #pragma unroll
        for (int f = 0; f < 4; ++f)
            b[f] = *reinterpret_cast<short8*>(&Bs[wn * 64 + f * 16 + lo][hi * 8]);
        #pragma unroll
        for (int fm = 0; fm < 4; ++fm)
            #pragma unroll
            for (int fn = 0; fn < 4; ++fn)
                acc[fm][fn] = __builtin_amdgcn_mfma_f32_16x16x32_bf16(
                    a[fm], b[fn], acc[fm][fn], 0, 0, 0);
        __syncthreads();
    }

    #pragma unroll
    for (int fm = 0; fm < 4; ++fm) {
        #pragma unroll
        for (int fn = 0; fn < 4; ++fn) {
            #pragma unroll
            for (int r = 0; r < 4; ++r) {
                int gm = m0 + wm * 64 + fm * 16 + hi * 4 + r;
                int gn = n0 + wn * 64 + fn * 16 + lo;
                if (gm < VOCAB) {
                    unsigned int sl = (unsigned int)gn / SCOLS;
                    unsigned int cc = (unsigned int)gn - sl * SCOLS;
                    P[((size_t)(sl * 3 + s) * VOCAB + gm) * SCOLS + cc] =
                        f2bf(acc[fm][fn][r]);
                }
            }
        }
    }
}

// ---------------------------------------------------------------------------
// token_sliced v3: double-buffered row-gather pipeline.
// Invariant at each phase: current pass's 14 rows already in flight; while
// accumulating them, the next pass's 14 rows + next-next ids are in flight.
// All register indices static (full unroll) to stay out of scratch.
// ---------------------------------------------------------------------------
__global__ __launch_bounds__(192) void token_sliced(
    const unsigned short* __restrict__ Ps, const short* __restrict__ idsU,
    const float* __restrict__ bias, const int* __restrict__ inv_i,
    float* __restrict__ out)
{
    const int slice = blockIdx.x & (NSLICE - 1);
    const int chunk = blockIdx.x >> 3;
    const int tid   = threadIdx.x;
    const int grp   = tid / 12;          // 0..15
    const int lj    = tid - grp * 12;    // 0..11

    const unsigned short* P0 = Ps + (size_t)slice * 3 * VOCAB * SCOLS;
    const int cbase = slice * SCOLS + lj * 8;
    const int coff  = lj * 8;

    const f32x4 bv0 = *reinterpret_cast<const f32x4*>(&bias[cbase]);
    const f32x4 bv1 = *reinterpret_cast<const f32x4*>(&bias[cbase + 4]);

    const int tbase = chunk * TOKS_PER_BLK + grp;
    int us[PASSES];
    #pragma unroll
    for (int p = 0; p < PASSES; ++p) us[p] = inv_i[tbase + p * 16];

#define LD_IDS(lo_, hi_, u_) \
    lo_ = *reinterpret_cast<const short8*>(&idsU[(size_t)(u_) * 16]); \
    hi_ = *reinterpret_cast<const short8*>(&idsU[(size_t)(u_) * 16 + 8]);

#define ISSUE_ROWS(r_, lo_, hi_) \
    _Pragma("unroll") \
    for (int s_ = 0; s_ < 14; ++s_) { \
        int idf_ = (unsigned short)(s_ < 8 ? (lo_)[s_] : (hi_)[s_ - 8]); \
        (r_)[s_] = *reinterpret_cast<const short8*>( \
            &P0[(size_t)idf_ * SCOLS + coff]); \
    }

#define ACC_STORE(r_, p_) { \
    float acc[8] = {bv0.x, bv0.y, bv0.z, bv0.w, bv1.x, bv1.y, bv1.z, bv1.w}; \
    _Pragma("unroll") \
    for (int s_ = 0; s_ < 14; ++s_) { \
        u32x4 w_ = __builtin_bit_cast(u32x4, (r_)[s_]); \
        _Pragma("unroll") \
        for (int j_ = 0; j_ < 4; ++j_) { \
            acc[2 * j_]     += bitsf(w_[j_] << 16); \
            acc[2 * j_ + 1] += bitsf(w_[j_] & 0xffff0000u); \
        } \
    } \
    const int t_ = tbase + (p_) * 16; \
    const int b_ = t_ >> 11; \
    const int l_ = t_ & (SEQ - 1); \
    float* dst_ = &out[((size_t)(b_ * (SEQ + 2) + l_ + 1)) * OUT + cbase]; \
    f32x4 o0_ = {acc[0], acc[1], acc[2], acc[3]}; \
    f32x4 o1_ = {acc[4], acc[5], acc[6], acc[7]}; \
    __builtin_nontemporal_store(o0_, reinterpret_cast<f32x4*>(dst_)); \
    __builtin_nontemporal_store(o1_, reinterpret_cast<f32x4*>(dst_ + 4)); }

    short8 rA[14], rB[14];
    short8 iAlo, iAhi, iBlo, iBhi;

    // prologue: ids(0) -> rows(0) in rA; ids(1) ready in iB
    LD_IDS(iAlo, iAhi, us[0]);
    LD_IDS(iBlo, iBhi, us[1]);
    ISSUE_ROWS(rA, iAlo, iAhi);

    #pragma unroll
    for (int h = 0; h < PASSES / 2; ++h) {
        const int p0 = 2 * h;
        // issue rows(p0+1) from iB
        ISSUE_ROWS(rB, iBlo, iBhi);
        // load ids(p0+2) into iA
        if (p0 + 2 < PASSES) { LD_IDS(iAlo, iAhi, us[p0 + 2]); }
        // accumulate + store pass p0 (waits only on rA)
        ACC_STORE(rA, p0);
        // issue rows(p0+2) from iA
        if (p0 + 2 < PASSES) { ISSUE_ROWS(rA, iAlo, iAhi); }
        // load ids(p0+3) into iB
        if (p0 + 3 < PASSES) { LD_IDS(iBlo, iBhi, us[p0 + 3]); }
        // accumulate + store pass p0+1 (waits only on rB)
        ACC_STORE(rB, p0 + 1);
    }
#undef LD_IDS
#undef ISSUE_ROWS
#undef ACC_STORE
}

// ---------------------------------------------------------------------------
__global__ void zero_pads(float* __restrict__ out)
{
    int j = blockIdx.x * blockDim.x + threadIdx.x;   // float4 index
    const int n4 = OUT / 4;                          // 192
    if (j >= BATCH * 2 * n4) return;
    int b  = j / (2 * n4);
    int r  = (j / n4) & 1;
    int c4 = j % n4;
    int row = r ? (SEQ + 1) : 0;
    f32x4 z = {};
    *reinterpret_cast<f32x4*>(
        &out[((size_t)(b * (SEQ + 2) + row)) * OUT + c4 * 4]) = z;
}

// ---------------------------------------------------------------------------
extern "C" void kernel_launch(void* const* d_in, const int* in_sizes, int n_in,
                              void* d_out, int out_size, void* d_ws, size_t ws_size,
                              hipStream_t stream)
{
    const float* emb    = (const float*)d_in[0];
    const float* head_w = (const float*)d_in[1];
    const float* head_b = (const float*)d_in[2];
    const int*   first  = (const int*)d_in[3];
    const int*   mid    = (const int*)d_in[4];
    const int*   last   = (const int*)d_in[5];
    const int*   inv_i  = (const int*)d_in[6];
    float* out = (float*)d_out;

    char* ws = (char*)d_ws;
    unsigned short* P    = (unsigned short*)ws;               // 18,432,000 B
    unsigned short* Wt   = (unsigned short*)(ws + 18432000);  //  1,179,648 B
    short*          idsU = (short*)(ws + 19611648);           //    960,000 B

    build_ids<<<(UNIQ + 255) / 256, 256, 0, stream>>>(first, mid, last, idsU);

    dim3 gw(OUT / 32, HID / 32, 3);
    conv_w<<<gw, 256, 0, stream>>>(head_w, Wt);

    dim3 g1(OUT / 128, (VOCAB + 127) / 128, 3);   // 6 x 32 x 3
    proj_mfma<<<g1, 256, 0, stream>>>(emb, Wt, P);

    const int nblk = (BATCH * SEQ / TOKS_PER_BLK) * NSLICE;   // 2048
    token_sliced<<<nblk, 192, 0, stream>>>(P, idsU, head_b, inv_i, out);

    const int pad4 = BATCH * 2 * (OUT / 4);
    zero_pads<<<(pad4 + 255) / 256, 256, 0, stream>>>(out);
}

// Round 6
// 70.379 us; speedup vs baseline: 1.0908x; 1.0908x over previous
//
#include <hip/hip_runtime.h>

#define VOCAB 4000
#define UNIQ 30000
#define MIDN 12
#define HID 256
#define OUT 768
#define BATCH 16
#define SEQ 2048

#define NXCD 8
#define XCOLS 96            // cols per xcd slice
#define SUBC 16             // cols per sub-slice
#define NSUB 48             // OUT / SUBC
#define TCHUNK 2048         // tokens per block
#define NCHUNK 16           // 32768 / TCHUNK
#define TPASS 256           // tokens per pass (1024 thr / 4 lanes-per-token)
#define NPASS 8             // TCHUNK / TPASS
#define PLANE 32008         // LDS plane stride: 4000*8 + 8 (bank skew), 4*32008=128032 B

typedef __attribute__((ext_vector_type(8))) short short8;   // 8 bf16 = 16B
typedef __attribute__((ext_vector_type(4))) float f32x4;

__device__ __forceinline__ float bitsf(unsigned int x) {
    float f; __builtin_memcpy(&f, &x, 4); return f;
}
__device__ __forceinline__ unsigned short f2bf(float f) {
    unsigned int x;
    __builtin_memcpy(&x, &f, 4);
    x += 0x7fff + ((x >> 16) & 1);   // round-to-nearest-even
    return (unsigned short)(x >> 16);
}

// ---------------------------------------------------------------------------
// build_idsT: idsT[t][16] = {first[u], mid[u][0..11], last[u], 0, 0} (raw ids),
// u = inv_i[t]. Linear by token -> later reads are fully sequential.
// ---------------------------------------------------------------------------
__global__ __launch_bounds__(256) void build_idsT(
    const int* __restrict__ first, const int* __restrict__ mid,
    const int* __restrict__ last, const int* __restrict__ inv_i,
    short* __restrict__ idsT)
{
    int t = blockIdx.x * 256 + threadIdx.x;
    if (t >= BATCH * SEQ) return;
    int u = inv_i[t];
    int4 m0 = *reinterpret_cast<const int4*>(&mid[u * MIDN]);
    int4 m1 = *reinterpret_cast<const int4*>(&mid[u * MIDN + 4]);
    int4 m2 = *reinterpret_cast<const int4*>(&mid[u * MIDN + 8]);
    short ids[16];
    ids[0]  = (short)first[u];
    ids[1]  = (short)m0.x; ids[2]  = (short)m0.y; ids[3]  = (short)m0.z; ids[4]  = (short)m0.w;
    ids[5]  = (short)m1.x; ids[6]  = (short)m1.y; ids[7]  = (short)m1.z; ids[8]  = (short)m1.w;
    ids[9]  = (short)m2.x; ids[10] = (short)m2.y; ids[11] = (short)m2.z; ids[12] = (short)m2.w;
    ids[13] = (short)last[u];
    ids[14] = 0; ids[15] = 0;
    *reinterpret_cast<short8*>(&idsT[(size_t)t * 16])     = *reinterpret_cast<short8*>(&ids[0]);
    *reinterpret_cast<short8*>(&idsT[(size_t)t * 16 + 8]) = *reinterpret_cast<short8*>(&ids[8]);
}

// ---------------------------------------------------------------------------
// conv_w: W (768x768 fp32) -> Wt bf16 [3][768][256] via LDS transpose tiles.
// ---------------------------------------------------------------------------
__global__ __launch_bounds__(256) void conv_w(
    const float* __restrict__ W, unsigned short* __restrict__ Wt)
{
    __shared__ float T[32][33];
    const int s  = blockIdx.z;
    const int n0 = blockIdx.x * 32;
    const int h0 = blockIdx.y * 32;
    const int tx = threadIdx.x & 31;
    const int ty = threadIdx.x >> 5;

    #pragma unroll
    for (int k = 0; k < 4; ++k) {
        int h = ty + 8 * k;
        T[h][tx] = W[(size_t)(s * HID + h0 + h) * OUT + n0 + tx];
    }
    __syncthreads();
    #pragma unroll
    for (int k = 0; k < 4; ++k) {
        int n = ty + 8 * k;
        Wt[(size_t)(s * OUT + n0 + n) * HID + h0 + tx] = f2bf(T[tx][n]);
    }
}

// ---------------------------------------------------------------------------
// proj_mfma: P[xcd][s][v][96cols] = sum_h E[v][h] * W[s*256+h][xcd*96+c]
// Additionally writes the mid table (s==1) in sub-sliced layout
// Pmid[sub][4000][16] for LDS staging.
// ---------------------------------------------------------------------------
__global__ __launch_bounds__(256) void proj_mfma(
    const float* __restrict__ E,
    const unsigned short* __restrict__ Wt,
    unsigned short* __restrict__ P,
    unsigned short* __restrict__ Pmid)
{
    const int s  = blockIdx.z;
    const int n0 = blockIdx.x * 128;
    const int m0 = blockIdx.y * 128;
    const unsigned short* Wts = Wt + (size_t)s * OUT * HID;

    __shared__ short As[128][40];   // 80B pitch
    __shared__ short Bs[128][40];

    const int tid  = threadIdx.x;
    const int lane = tid & 63;
    const int w    = tid >> 6;
    const int wm   = w >> 1;
    const int wn   = w & 1;
    const int lo   = lane & 15;
    const int hi   = lane >> 4;

    f32x4 acc[4][4] = {};

    for (int kt = 0; kt < HID; kt += 32) {
        #pragma unroll
        for (int p = 0; p < 2; ++p) {
            int idx = p * 256 + tid;
            int row = idx >> 2;
            int ko  = (idx & 3) * 8;
            int gm  = m0 + row;
            f32x4 e0 = {}, e1 = {};
            if (gm < VOCAB) {
                e0 = *reinterpret_cast<const f32x4*>(&E[(size_t)gm * HID + kt + ko]);
                e1 = *reinterpret_cast<const f32x4*>(&E[(size_t)gm * HID + kt + ko + 4]);
            }
            short8 v;
            v[0] = (short)f2bf(e0.x); v[1] = (short)f2bf(e0.y);
            v[2] = (short)f2bf(e0.z); v[3] = (short)f2bf(e0.w);
            v[4] = (short)f2bf(e1.x); v[5] = (short)f2bf(e1.y);
            v[6] = (short)f2bf(e1.z); v[7] = (short)f2bf(e1.w);
            *reinterpret_cast<short8*>(&As[row][ko]) = v;
        }
        #pragma unroll
        for (int p = 0; p < 2; ++p) {
            int idx = p * 256 + tid;
            int col = idx >> 2;
            int ko  = (idx & 3) * 8;
            short8 v = *reinterpret_cast<const short8*>(
                &Wts[(size_t)(n0 + col) * HID + kt + ko]);
            *reinterpret_cast<short8*>(&Bs[col][ko]) = v;
        }
        __syncthreads();

        short8 a[4], b[4];
        #pragma unroll
        for (int f = 0; f < 4; ++f)
            a[f] = *reinterpret_cast<short8*>(&As[wm * 64 + f * 16 + lo][hi * 8]);
        #pragma unroll
        for (int f = 0; f < 4; ++f)
            b[f] = *reinterpret_cast<short8*>(&Bs[wn * 64 + f * 16 + lo][hi * 8]);
        #pragma unroll
        for (int fm = 0; fm < 4; ++fm)
            #pragma unroll
            for (int fn = 0; fn < 4; ++fn)
                acc[fm][fn] = __builtin_amdgcn_mfma_f32_16x16x32_bf16(
                    a[fm], b[fn], acc[fm][fn], 0, 0, 0);
        __syncthreads();
    }

    #pragma unroll
    for (int fm = 0; fm < 4; ++fm) {
        #pragma unroll
        for (int fn = 0; fn < 4; ++fn) {
            #pragma unroll
            for (int r = 0; r < 4; ++r) {
                int gm = m0 + wm * 64 + fm * 16 + hi * 4 + r;
                int gn = n0 + wn * 64 + fn * 16 + lo;
                if (gm < VOCAB) {
                    unsigned short val = f2bf(acc[fm][fn][r]);
                    unsigned int sl = (unsigned int)gn / XCOLS;
                    unsigned int cc = (unsigned int)gn - sl * XCOLS;
                    P[((size_t)(sl * 3 + s) * VOCAB + gm) * XCOLS + cc] = val;
                    if (s == 1) {
                        // sub-sliced copy of the mid table
                        Pmid[((size_t)(gn >> 4) * VOCAB + gm) * SUBC + (gn & 15)] = val;
                    }
                }
            }
        }
    }
}

// ---------------------------------------------------------------------------
// token_lds: per-(16-col sub-slice, 2048-token chunk) block.
//  - stages the mid sub-slice (4000x16 bf16) into 128 KB LDS once
//    (4 planes skewed by 32008 B -> 16 bank-bases, conflict-light)
//  - per token: 12 mid reads from LDS (no VMEM lines), first/last 32 B
//    global gathers (XCD-L2-local via blockIdx&7 affinity), ids streamed
//    sequentially from idsT with 4-lane shfl broadcast.
// ---------------------------------------------------------------------------
extern __shared__ char lds_raw[];

__global__ __launch_bounds__(1024) void token_lds(
    const unsigned short* __restrict__ P,      // [8][3][4000][96]
    const unsigned short* __restrict__ Pmid,   // [48][4000][16]
    const short* __restrict__ idsT,            // [32768][16]
    const float* __restrict__ bias,
    float* __restrict__ out)
{
    const int bid   = blockIdx.x;              // (chunk*6 + s6)*8 + xcd
    const int xcd   = bid & 7;
    const int r     = bid >> 3;
    const int s6    = r % 6;
    const int chunk = r / 6;
    const int sub   = xcd * 6 + s6;

    const int tid = threadIdx.x;
    const int l4  = tid & 3;
    const int grp = tid >> 2;                  // 0..255: token group
    const int lane = tid & 63;
    const int gbase = lane & ~3;               // group base lane in wave

    // ---- stage Pmid[sub] into LDS ----
    {
        const unsigned short* src = Pmid + (size_t)sub * VOCAB * SUBC;
        #pragma unroll
        for (int i = 0; i < 16; ++i) {
            int idx = i * 1024 + tid;          // 0..16383; need 16000
            if (idx < VOCAB * 4) {
                int row = idx >> 2;
                int q   = idx & 3;
                uint2 v = *reinterpret_cast<const uint2*>(&src[row * SUBC + q * 4]);
                *reinterpret_cast<uint2*>(lds_raw + q * PLANE + row * 8) = v;
            }
        }
    }
    __syncthreads();

    char* myplane = lds_raw + l4 * PLANE;

    const int csub = s6 * SUBC + l4 * 4;                 // col offset in 96-wide slice
    const int colc = xcd * XCOLS + csub;                 // absolute col
    const unsigned short* P0 = P + (size_t)xcd * 3 * VOCAB * XCOLS + csub;
    const unsigned short* P2 = P0 + (size_t)2 * VOCAB * XCOLS;

    const f32x4 bv = *reinterpret_cast<const f32x4*>(&bias[colc]);

    const int t0 = chunk * TCHUNK + grp;
    uint2 idv = *reinterpret_cast<const uint2*>(&idsT[(size_t)t0 * 16 + l4 * 4]);

    #pragma unroll 1
    for (int p = 0; p < NPASS; ++p) {
        const int t = t0 + p * TPASS;

        // broadcast the token's 16 ids across the 4-lane group
        unsigned int w[8];
        #pragma unroll
        for (int s = 0; s < 4; ++s) {
            w[2 * s]     = __shfl(idv.x, gbase + s, 64);
            w[2 * s + 1] = __shfl(idv.y, gbase + s, 64);
        }
        const int fid = (int)(w[0] & 0xffffu);           // ids[0]
        const int lid = (int)(w[6] >> 16);               // ids[13]

        // long-latency global loads first
        uint2 fv = *reinterpret_cast<const uint2*>(&P0[(size_t)fid * XCOLS]);
        uint2 lv = *reinterpret_cast<const uint2*>(&P2[(size_t)lid * XCOLS]);
        if (p + 1 < NPASS)
            idv = *reinterpret_cast<const uint2*>(
                &idsT[(size_t)(t + TPASS) * 16 + l4 * 4]);

        // 12 mid reads from LDS
        uint2 mv[MIDN];
        #pragma unroll
        for (int m = 0; m < MIDN; ++m) {
            int k = m + 1;
            int rid = (int)((w[k >> 1] >> ((k & 1) * 16)) & 0xffffu);
            mv[m] = *reinterpret_cast<const uint2*>(myplane + rid * 8);
        }

        float a0 = bv.x, a1 = bv.y, a2 = bv.z, a3 = bv.w;
        #pragma unroll
        for (int m = 0; m < MIDN; ++m) {
            a0 += bitsf(mv[m].x << 16);
            a1 += bitsf(mv[m].x & 0xffff0000u);
            a2 += bitsf(mv[m].y << 16);
            a3 += bitsf(mv[m].y & 0xffff0000u);
        }
        a0 += bitsf(fv.x << 16); a1 += bitsf(fv.x & 0xffff0000u);
        a2 += bitsf(fv.y << 16); a3 += bitsf(fv.y & 0xffff0000u);
        a0 += bitsf(lv.x << 16); a1 += bitsf(lv.x & 0xffff0000u);
        a2 += bitsf(lv.y << 16); a3 += bitsf(lv.y & 0xffff0000u);

        const int b = t >> 11;
        const int l = t & (SEQ - 1);
        float* dst = &out[((size_t)(b * (SEQ + 2) + l + 1)) * OUT + colc];
        f32x4 o = {a0, a1, a2, a3};
        __builtin_nontemporal_store(o, reinterpret_cast<f32x4*>(dst));
    }
}

// ---------------------------------------------------------------------------
__global__ void zero_pads(float* __restrict__ out)
{
    int j = blockIdx.x * blockDim.x + threadIdx.x;   // float4 index
    const int n4 = OUT / 4;                          // 192
    if (j >= BATCH * 2 * n4) return;
    int b  = j / (2 * n4);
    int r  = (j / n4) & 1;
    int c4 = j % n4;
    int row = r ? (SEQ + 1) : 0;
    f32x4 z = {};
    *reinterpret_cast<f32x4*>(
        &out[((size_t)(b * (SEQ + 2) + row)) * OUT + c4 * 4]) = z;
}

// ---------------------------------------------------------------------------
extern "C" void kernel_launch(void* const* d_in, const int* in_sizes, int n_in,
                              void* d_out, int out_size, void* d_ws, size_t ws_size,
                              hipStream_t stream)
{
    const float* emb    = (const float*)d_in[0];
    const float* head_w = (const float*)d_in[1];
    const float* head_b = (const float*)d_in[2];
    const int*   first  = (const int*)d_in[3];
    const int*   mid    = (const int*)d_in[4];
    const int*   last   = (const int*)d_in[5];
    const int*   inv_i  = (const int*)d_in[6];
    float* out = (float*)d_out;

    char* ws = (char*)d_ws;
    unsigned short* P    = (unsigned short*)ws;               // 18,432,000 B
    unsigned short* Wt   = (unsigned short*)(ws + 18432000);  //  1,179,648 B
    unsigned short* Pmid = (unsigned short*)(ws + 19611648);  //  6,144,000 B
    short*          idsT = (short*)(ws + 25755648);           //  1,048,576 B

    build_idsT<<<(BATCH * SEQ + 255) / 256, 256, 0, stream>>>(
        first, mid, last, inv_i, idsT);

    dim3 gw(OUT / 32, HID / 32, 3);
    conv_w<<<gw, 256, 0, stream>>>(head_w, Wt);

    dim3 g1(OUT / 128, (VOCAB + 127) / 128, 3);   // 6 x 32 x 3
    proj_mfma<<<g1, 256, 0, stream>>>(emb, Wt, P, Pmid);

    token_lds<<<NCHUNK * 6 * NXCD, 1024, 4 * PLANE, stream>>>(
        P, Pmid, idsT, head_b, out);

    const int pad4 = BATCH * 2 * (OUT / 4);
    zero_pads<<<(pad4 + 255) / 256, 256, 0, stream>>>(out);
}

// Round 7
// 67.107 us; speedup vs baseline: 1.1440x; 1.0488x over previous
//
#include <hip/hip_runtime.h>

#define VOCAB 4000
#define UNIQ 30000
#define MIDN 12
#define HID 256
#define OUT 768
#define BATCH 16
#define SEQ 2048

#define NXCD 8
#define XCOLS 96            // cols per xcd slice
#define SUBC 16             // cols per sub-slice
#define TCHUNK 2048         // tokens per chunk
#define NCHUNK 16           // 32768 / TCHUNK
#define TPASS 256           // tokens per pass (1024 thr / 4 lanes-per-token)
#define NPASS 8             // TCHUNK / TPASS
#define PLANE 32008         // LDS plane stride: 4000*8 + 8 (bank skew)

typedef __attribute__((ext_vector_type(8))) short short8;   // 8 bf16 = 16B
typedef __attribute__((ext_vector_type(4))) float f32x4;
typedef __attribute__((ext_vector_type(4))) unsigned int u32x4;
typedef __attribute__((ext_vector_type(2))) unsigned int u32x2;

__device__ __forceinline__ float bitsf(unsigned int x) {
    float f; __builtin_memcpy(&f, &x, 4); return f;
}
__device__ __forceinline__ unsigned short f2bf(float f) {
    unsigned int x;
    __builtin_memcpy(&x, &f, 4);
    x += 0x7fff + ((x >> 16) & 1);   // round-to-nearest-even
    return (unsigned short)(x >> 16);
}

// ---------------------------------------------------------------------------
// build_idsT: idsT[t][16] = {first[u], mid[u][0..11], last[u], 0, 0},
// u = inv_i[t]. Linear by token -> later reads fully sequential.
// ---------------------------------------------------------------------------
__global__ __launch_bounds__(256) void build_idsT(
    const int* __restrict__ first, const int* __restrict__ mid,
    const int* __restrict__ last, const int* __restrict__ inv_i,
    short* __restrict__ idsT)
{
    int t = blockIdx.x * 256 + threadIdx.x;
    if (t >= BATCH * SEQ) return;
    int u = inv_i[t];
    int4 m0 = *reinterpret_cast<const int4*>(&mid[u * MIDN]);
    int4 m1 = *reinterpret_cast<const int4*>(&mid[u * MIDN + 4]);
    int4 m2 = *reinterpret_cast<const int4*>(&mid[u * MIDN + 8]);
    short ids[16];
    ids[0]  = (short)first[u];
    ids[1]  = (short)m0.x; ids[2]  = (short)m0.y; ids[3]  = (short)m0.z; ids[4]  = (short)m0.w;
    ids[5]  = (short)m1.x; ids[6]  = (short)m1.y; ids[7]  = (short)m1.z; ids[8]  = (short)m1.w;
    ids[9]  = (short)m2.x; ids[10] = (short)m2.y; ids[11] = (short)m2.z; ids[12] = (short)m2.w;
    ids[13] = (short)last[u];
    ids[14] = 0; ids[15] = 0;
    *reinterpret_cast<short8*>(&idsT[(size_t)t * 16])     = *reinterpret_cast<short8*>(&ids[0]);
    *reinterpret_cast<short8*>(&idsT[(size_t)t * 16 + 8]) = *reinterpret_cast<short8*>(&ids[8]);
}

// ---------------------------------------------------------------------------
// conv_w: W (768x768 fp32) -> Wt bf16 [3][768][256] via LDS transpose tiles.
// ---------------------------------------------------------------------------
__global__ __launch_bounds__(256) void conv_w(
    const float* __restrict__ W, unsigned short* __restrict__ Wt)
{
    __shared__ float T[32][33];
    const int s  = blockIdx.z;
    const int n0 = blockIdx.x * 32;
    const int h0 = blockIdx.y * 32;
    const int tx = threadIdx.x & 31;
    const int ty = threadIdx.x >> 5;

    #pragma unroll
    for (int k = 0; k < 4; ++k) {
        int h = ty + 8 * k;
        T[h][tx] = W[(size_t)(s * HID + h0 + h) * OUT + n0 + tx];
    }
    __syncthreads();
    #pragma unroll
    for (int k = 0; k < 4; ++k) {
        int n = ty + 8 * k;
        Wt[(size_t)(s * OUT + n0 + n) * HID + h0 + tx] = f2bf(T[tx][n]);
    }
}

// ---------------------------------------------------------------------------
// proj_mfma: for s in {0,2}: P[xcd][s'][v][96] (s'=0 first, 1 last)
//            for s==1:      Pmid[sub][4000][16]  (sub-tiled for LDS staging)
// 128x128 tile, 4 waves, BK=32, mfma_f32_16x16x32_bf16.
// ---------------------------------------------------------------------------
__global__ __launch_bounds__(256) void proj_mfma(
    const float* __restrict__ E,
    const unsigned short* __restrict__ Wt,
    unsigned short* __restrict__ P,
    unsigned short* __restrict__ Pmid)
{
    const int s  = blockIdx.z;
    const int n0 = blockIdx.x * 128;
    const int m0 = blockIdx.y * 128;
    const unsigned short* Wts = Wt + (size_t)s * OUT * HID;

    __shared__ short As[128][40];   // 80B pitch
    __shared__ short Bs[128][40];

    const int tid  = threadIdx.x;
    const int lane = tid & 63;
    const int w    = tid >> 6;
    const int wm   = w >> 1;
    const int wn   = w & 1;
    const int lo   = lane & 15;
    const int hi   = lane >> 4;

    f32x4 acc[4][4] = {};

    for (int kt = 0; kt < HID; kt += 32) {
        #pragma unroll
        for (int p = 0; p < 2; ++p) {
            int idx = p * 256 + tid;
            int row = idx >> 2;
            int ko  = (idx & 3) * 8;
            int gm  = m0 + row;
            f32x4 e0 = {}, e1 = {};
            if (gm < VOCAB) {
                e0 = *reinterpret_cast<const f32x4*>(&E[(size_t)gm * HID + kt + ko]);
                e1 = *reinterpret_cast<const f32x4*>(&E[(size_t)gm * HID + kt + ko + 4]);
            }
            short8 v;
            v[0] = (short)f2bf(e0.x); v[1] = (short)f2bf(e0.y);
            v[2] = (short)f2bf(e0.z); v[3] = (short)f2bf(e0.w);
            v[4] = (short)f2bf(e1.x); v[5] = (short)f2bf(e1.y);
            v[6] = (short)f2bf(e1.z); v[7] = (short)f2bf(e1.w);
            *reinterpret_cast<short8*>(&As[row][ko]) = v;
        }
        #pragma unroll
        for (int p = 0; p < 2; ++p) {
            int idx = p * 256 + tid;
            int col = idx >> 2;
            int ko  = (idx & 3) * 8;
            short8 v = *reinterpret_cast<const short8*>(
                &Wts[(size_t)(n0 + col) * HID + kt + ko]);
            *reinterpret_cast<short8*>(&Bs[col][ko]) = v;
        }
        __syncthreads();

        short8 a[4], b[4];
        #pragma unroll
        for (int f = 0; f < 4; ++f)
            a[f] = *reinterpret_cast<short8*>(&As[wm * 64 + f * 16 + lo][hi * 8]);
        #pragma unroll
        for (int f = 0; f < 4; ++f)
            b[f] = *reinterpret_cast<short8*>(&Bs[wn * 64 + f * 16 + lo][hi * 8]);
        #pragma unroll
        for (int fm = 0; fm < 4; ++fm)
            #pragma unroll
            for (int fn = 0; fn < 4; ++fn)
                acc[fm][fn] = __builtin_amdgcn_mfma_f32_16x16x32_bf16(
                    a[fm], b[fn], acc[fm][fn], 0, 0, 0);
        __syncthreads();
    }

    #pragma unroll
    for (int fm = 0; fm < 4; ++fm) {
        #pragma unroll
        for (int fn = 0; fn < 4; ++fn) {
            #pragma unroll
            for (int r = 0; r < 4; ++r) {
                int gm = m0 + wm * 64 + fm * 16 + hi * 4 + r;
                int gn = n0 + wn * 64 + fn * 16 + lo;
                if (gm < VOCAB) {
                    unsigned short val = f2bf(acc[fm][fn][r]);
                    if (s == 1) {
                        Pmid[((size_t)(gn >> 4) * VOCAB + gm) * SUBC + (gn & 15)] = val;
                    } else {
                        int so = (s == 0) ? 0 : 1;
                        unsigned int sl = (unsigned int)gn / XCOLS;
                        unsigned int cc = (unsigned int)gn - sl * XCOLS;
                        P[(((size_t)sl * 2 + so) * VOCAB + gm) * XCOLS + cc] = val;
                    }
                }
            }
        }
    }
}

// ---------------------------------------------------------------------------
// token_lds v2: persistent blocks (grid = 256, 1/CU), xcd-affine tasks.
// Per xcd (bid&7): 32 blocks x 3 tasks cover 6 subs x 16 chunks; LDS restaged
// only when the sub changes. Per pass, a 2-ahead pipeline keeps fv/lv and ids
// loads a full pass ahead of their use. No shfls: each lane loads the token's
// full 32-B id row (same addr in 4-lane group -> cache broadcast).
// ---------------------------------------------------------------------------
extern __shared__ char lds_raw[];

__global__ __launch_bounds__(1024) void token_lds(
    const unsigned short* __restrict__ P,      // [8][2][4000][96]
    const unsigned short* __restrict__ Pmid,   // [48][4000][16]
    const short* __restrict__ idsT,            // [32768][16]
    const float* __restrict__ bias,
    float* __restrict__ out)
{
    const int xcd = blockIdx.x & 7;
    const int bi  = blockIdx.x >> 3;           // 0..31

    const int tid = threadIdx.x;
    const int l4  = tid & 3;
    const int grp = tid >> 2;                  // 0..255 token group

    char* myplane = lds_raw + l4 * PLANE;
    const unsigned short* Pbase = P + (size_t)xcd * 2 * VOCAB * XCOLS;

    int cur_sl = -1;

    #pragma unroll 1
    for (int k = 0; k < 3; ++k) {
        const int task = bi * 3 + k;           // 0..95
        const int sl   = task >> 4;            // 0..5
        const int ch   = task & 15;            // chunk

        if (sl != cur_sl) {
            if (cur_sl >= 0) __syncthreads();
            const int sub = xcd * 6 + sl;
            const unsigned short* src = Pmid + (size_t)sub * VOCAB * SUBC;
            #pragma unroll
            for (int i = 0; i < 16; ++i) {
                int idx = i * 1024 + tid;
                if (idx < VOCAB * 4) {
                    int row = idx >> 2;
                    int q   = idx & 3;
                    uint2 v = *reinterpret_cast<const uint2*>(&src[row * SUBC + q * 4]);
                    *reinterpret_cast<uint2*>(lds_raw + q * PLANE + row * 8) = v;
                }
            }
            __syncthreads();
            cur_sl = sl;
        }

        const int csub = sl * SUBC + l4 * 4;
        const int colc = xcd * XCOLS + csub;
        const unsigned short* P0 = Pbase + csub;
        const unsigned short* P2 = Pbase + (size_t)VOCAB * XCOLS + csub;
        const f32x4 bv = *reinterpret_cast<const f32x4*>(&bias[colc]);

        const int t0 = ch * TCHUNK + grp;

#define LDIDS(lo_, hi_, tt_) { \
        const u32x4* _r = reinterpret_cast<const u32x4*>(&idsT[(size_t)(tt_) * 16]); \
        lo_ = _r[0]; hi_ = _r[1]; }

#define GATHER(fv_, lv_, lo_, hi_) { \
        int _fid = (int)((lo_).x & 0xffffu); \
        int _lid = (int)((hi_).z >> 16); \
        fv_ = *reinterpret_cast<const uint2*>(&P0[(size_t)_fid * XCOLS]); \
        lv_ = *reinterpret_cast<const uint2*>(&P2[(size_t)_lid * XCOLS]); }

        u32x4 ilA, ihA, ilB, ihB;
        uint2 fvA, lvA, fvB, lvB;

        // prologue: ids(0), ids(1); fv/lv(0)
        LDIDS(ilA, ihA, t0);
        LDIDS(ilB, ihB, t0 + TPASS);
        GATHER(fvA, lvA, ilA, ihA);

        #pragma unroll
        for (int p = 0; p < NPASS; ++p) {
            const bool even = (p & 1) == 0;
            u32x4 clo = even ? ilA : ilB;
            u32x4 chi = even ? ihA : ihB;
            uint2 cfv = even ? fvA : fvB;
            uint2 clv = even ? lvA : lvB;

            // issue next pass's fv/lv (ids already resident)
            if (p + 1 < NPASS) {
                if (even) { GATHER(fvB, lvB, ilB, ihB); }
                else      { GATHER(fvA, lvA, ilA, ihA); }
            }
            // load ids two passes ahead into the slot just freed
            if (p + 2 < NPASS) {
                if (even) { LDIDS(ilA, ihA, t0 + (p + 2) * TPASS); }
                else      { LDIDS(ilB, ihB, t0 + (p + 2) * TPASS); }
            }

            // 12 mid rows from LDS
            int rid[MIDN];
            rid[0]  = (int)(clo.x >> 16);
            rid[1]  = (int)(clo.y & 0xffffu);
            rid[2]  = (int)(clo.y >> 16);
            rid[3]  = (int)(clo.z & 0xffffu);
            rid[4]  = (int)(clo.z >> 16);
            rid[5]  = (int)(clo.w & 0xffffu);
            rid[6]  = (int)(clo.w >> 16);
            rid[7]  = (int)(chi.x & 0xffffu);
            rid[8]  = (int)(chi.x >> 16);
            rid[9]  = (int)(chi.y & 0xffffu);
            rid[10] = (int)(chi.y >> 16);
            rid[11] = (int)(chi.z & 0xffffu);

            uint2 mv[MIDN];
            #pragma unroll
            for (int m = 0; m < MIDN; ++m)
                mv[m] = *reinterpret_cast<const uint2*>(myplane + rid[m] * 8);

            float a0 = bv.x, a1 = bv.y, a2 = bv.z, a3 = bv.w;
            #pragma unroll
            for (int m = 0; m < MIDN; ++m) {
                a0 += bitsf(mv[m].x << 16);
                a1 += bitsf(mv[m].x & 0xffff0000u);
                a2 += bitsf(mv[m].y << 16);
                a3 += bitsf(mv[m].y & 0xffff0000u);
            }
            a0 += bitsf(cfv.x << 16); a1 += bitsf(cfv.x & 0xffff0000u);
            a2 += bitsf(cfv.y << 16); a3 += bitsf(cfv.y & 0xffff0000u);
            a0 += bitsf(clv.x << 16); a1 += bitsf(clv.x & 0xffff0000u);
            a2 += bitsf(clv.y << 16); a3 += bitsf(clv.y & 0xffff0000u);

            const int t = t0 + p * TPASS;
            const int b = t >> 11;
            const int l = t & (SEQ - 1);
            float* dst = &out[((size_t)(b * (SEQ + 2) + l + 1)) * OUT + colc];
            f32x4 o = {a0, a1, a2, a3};
            __builtin_nontemporal_store(o, reinterpret_cast<f32x4*>(dst));
        }
#undef LDIDS
#undef GATHER
    }
}

// ---------------------------------------------------------------------------
__global__ void zero_pads(float* __restrict__ out)
{
    int j = blockIdx.x * blockDim.x + threadIdx.x;   // float4 index
    const int n4 = OUT / 4;                          // 192
    if (j >= BATCH * 2 * n4) return;
    int b  = j / (2 * n4);
    int r  = (j / n4) & 1;
    int c4 = j % n4;
    int row = r ? (SEQ + 1) : 0;
    f32x4 z = {};
    *reinterpret_cast<f32x4*>(
        &out[((size_t)(b * (SEQ + 2) + row)) * OUT + c4 * 4]) = z;
}

// ---------------------------------------------------------------------------
extern "C" void kernel_launch(void* const* d_in, const int* in_sizes, int n_in,
                              void* d_out, int out_size, void* d_ws, size_t ws_size,
                              hipStream_t stream)
{
    const float* emb    = (const float*)d_in[0];
    const float* head_w = (const float*)d_in[1];
    const float* head_b = (const float*)d_in[2];
    const int*   first  = (const int*)d_in[3];
    const int*   mid    = (const int*)d_in[4];
    const int*   last   = (const int*)d_in[5];
    const int*   inv_i  = (const int*)d_in[6];
    float* out = (float*)d_out;

    char* ws = (char*)d_ws;
    unsigned short* P    = (unsigned short*)ws;               // 12,288,000 B
    unsigned short* Wt   = (unsigned short*)(ws + 12288000);  //  1,179,648 B
    unsigned short* Pmid = (unsigned short*)(ws + 13467648);  //  6,144,000 B
    short*          idsT = (short*)(ws + 19611648);           //  1,048,576 B

    build_idsT<<<(BATCH * SEQ + 255) / 256, 256, 0, stream>>>(
        first, mid, last, inv_i, idsT);

    dim3 gw(OUT / 32, HID / 32, 3);
    conv_w<<<gw, 256, 0, stream>>>(head_w, Wt);

    dim3 g1(OUT / 128, (VOCAB + 127) / 128, 3);   // 6 x 32 x 3
    proj_mfma<<<g1, 256, 0, stream>>>(emb, Wt, P, Pmid);

    token_lds<<<256, 1024, 4 * PLANE, stream>>>(P, Pmid, idsT, head_b, out);

    const int pad4 = BATCH * 2 * (OUT / 4);
    zero_pads<<<(pad4 + 255) / 256, 256, 0, stream>>>(out);
}